// Round 2
// baseline (523.462 us; speedup 1.0000x reference)
//
#include <hip/hip_runtime.h>
#include <hip/hip_bf16.h>
#include <math.h>

// Problem constants (B=2, T=4096, D=2048, H=2048, W=4)
#define B_DIM 2
#define T_DIM 4096
#define D_DIM 2048
#define H_DIM 2048
#define W_K   4
#define M_DIM (B_DIM * T_DIM)   // 8192 tokens
#define N2_DIM (D_DIM * W_K)    // 8192

typedef __bf16 bf16x8 __attribute__((ext_vector_type(8)));
typedef float  f32x4  __attribute__((ext_vector_type(4)));

// 256x256 tile, K-tile 64, 8 waves (2M x 4N), 512 threads
#define BM 256
#define BN 256
#define BKT 64

__device__ __forceinline__ unsigned short f2bf(float f) {
    unsigned int u = __float_as_uint(f);
    unsigned int r = (u + 0x7FFFu + ((u >> 16) & 1u)) >> 16;  // RNE
    return (unsigned short)r;
}

__device__ __forceinline__ float silu_f(float v) {
    return v / (1.0f + __expf(-v));
}

__global__ void cvt_f32_to_bf16(const float* __restrict__ in,
                                unsigned short* __restrict__ out, int n4) {
    int i = blockIdx.x * blockDim.x + threadIdx.x;
    if (i >= n4) return;
    float4 v = reinterpret_cast<const float4*>(in)[i];
    ushort4 o;
    o.x = f2bf(v.x); o.y = f2bf(v.y); o.z = f2bf(v.z); o.w = f2bf(v.w);
    reinterpret_cast<ushort4*>(out)[i] = o;
}

// Read one MFMA fragment (bf16x8 = 16B) from a 32KB K-tile buffer laid out
// row-major [256 rows][64 cols bf16] with st_16x32 XOR swizzle on byte addr.
__device__ __forceinline__ bf16x8 lds_frag(const unsigned short* buf, int r, int kbyte) {
    int lin = r * 128 + kbyte;
    lin ^= ((lin >> 9) & 1) << 5;   // st_16x32
    return *reinterpret_cast<const bf16x8*>(reinterpret_cast<const char*>(buf) + lin);
}

// Stage one 8KB chunk (64 rows x 64 cols bf16) of a K-tile into LDS.
// LDS dest is linear (global_load_lds: wave-uniform base + lane*16); the
// st_16x32 swizzle is applied by INVERSE-swizzling the global source address
// (rule #21: both-sides-or-neither; XOR swizzle is an involution).
__device__ __forceinline__ void stage_chunk(const unsigned short* __restrict__ G,
                                            int row0, int K, int ko,
                                            unsigned short* lbuf, int chunk,
                                            int wave, int lane) {
    int db = chunk * 8192 + wave * 1024 + lane * 16;   // linear LDS byte offset
    int lb = db ^ (((db >> 9) & 1) << 5);              // logical (row,col) byte
    int row = lb >> 7;
    int cb  = lb & 127;
    const unsigned short* src = &G[(size_t)(row0 + row) * K + ko + (cb >> 1)];
    __builtin_amdgcn_global_load_lds(
        (const __attribute__((address_space(1))) void*)src,
        (__attribute__((address_space(3))) void*)(reinterpret_cast<char*>(lbuf) + db),
        16, 0, 0);
}

#define BARRIER()    __builtin_amdgcn_s_barrier()
#define WAIT_LGKM0() asm volatile("s_waitcnt lgkmcnt(0)" ::: "memory")
#define WAIT_VM(N)   asm volatile("s_waitcnt vmcnt(" #N ")" ::: "memory")

// 16 MFMA of one phase: M-group mg (2 Mfrags) x 4 Nfrags x 2 K-steps.
#define PH_MFMA(mg) \
    _Pragma("unroll") for (int kk = 0; kk < 2; ++kk) \
    _Pragma("unroll") for (int mrel = 0; mrel < 2; ++mrel) \
    _Pragma("unroll") for (int nf = 0; nf < 4; ++nf) \
        acc[(mg)*2 + mrel][nf] = __builtin_amdgcn_mfma_f32_16x16x32_bf16( \
            afrag[mrel][kk], bfrag[nf][kk], acc[(mg)*2 + mrel][nf], 0, 0, 0)

// One K-tile = 4 phases. Stage schedule (clobber-safe by last-read phase):
//   ph1: U_A2(j+1) -> other buf, A chunks 1,3   (A mg{2,3} of j-1 done at j-1 ph4)
//   ph2: U_B1(j+2) -> this buf,  B chunks 0,1   (B fully read at ph1)
//   ph3: U_A1(j+2) -> this buf,  A chunks 0,2   (A mg{0,1} read at ph1,ph2)
//   ph4: U_B2(j+2) -> this buf,  B chunks 2,3 ; vmcnt(6) = 3 half-tiles in flight
#define KTILE(bi, jj) do { \
    int j1 = (jj) + 1; if (j1 >= nk) j1 -= nk; \
    int j2 = (jj) + 2; if (j2 >= nk) j2 -= nk; \
    const int ko1 = j1 * BKT, ko2 = j2 * BKT; \
    /* ---- phase 1 (mg=0): read all B (8) + A mg0 (4) = 12 ds_read_b128 ---- */ \
    _Pragma("unroll") for (int nf = 0; nf < 4; ++nf) \
    _Pragma("unroll") for (int kk = 0; kk < 2; ++kk) \
        bfrag[nf][kk] = lds_frag(sB[bi], wc*64 + nf*16 + ln15, kk*64 + kb16); \
    _Pragma("unroll") for (int mrel = 0; mrel < 2; ++mrel) \
    _Pragma("unroll") for (int kk = 0; kk < 2; ++kk) \
        afrag[mrel][kk] = lds_frag(sA[bi], wr*128 + 0*32 + mrel*16 + ln15, kk*64 + kb16); \
    stage_chunk(A, m0, K, ko1, sA[(bi)^1], 1, wave, lane); \
    stage_chunk(A, m0, K, ko1, sA[(bi)^1], 3, wave, lane); \
    BARRIER(); WAIT_LGKM0(); \
    __builtin_amdgcn_s_setprio(1); PH_MFMA(0); __builtin_amdgcn_s_setprio(0); \
    BARRIER(); \
    /* ---- phase 2 (mg=1) ---- */ \
    _Pragma("unroll") for (int mrel = 0; mrel < 2; ++mrel) \
    _Pragma("unroll") for (int kk = 0; kk < 2; ++kk) \
        afrag[mrel][kk] = lds_frag(sA[bi], wr*128 + 1*32 + mrel*16 + ln15, kk*64 + kb16); \
    stage_chunk(Bm, n0, K, ko2, sB[bi], 0, wave, lane); \
    stage_chunk(Bm, n0, K, ko2, sB[bi], 1, wave, lane); \
    BARRIER(); WAIT_LGKM0(); \
    __builtin_amdgcn_s_setprio(1); PH_MFMA(1); __builtin_amdgcn_s_setprio(0); \
    BARRIER(); \
    /* ---- phase 3 (mg=2) ---- */ \
    _Pragma("unroll") for (int mrel = 0; mrel < 2; ++mrel) \
    _Pragma("unroll") for (int kk = 0; kk < 2; ++kk) \
        afrag[mrel][kk] = lds_frag(sA[bi], wr*128 + 2*32 + mrel*16 + ln15, kk*64 + kb16); \
    stage_chunk(A, m0, K, ko2, sA[bi], 0, wave, lane); \
    stage_chunk(A, m0, K, ko2, sA[bi], 2, wave, lane); \
    BARRIER(); WAIT_LGKM0(); \
    __builtin_amdgcn_s_setprio(1); PH_MFMA(2); __builtin_amdgcn_s_setprio(0); \
    BARRIER(); \
    /* ---- phase 4 (mg=3): counted vmcnt, never 0 in main loop ---- */ \
    _Pragma("unroll") for (int mrel = 0; mrel < 2; ++mrel) \
    _Pragma("unroll") for (int kk = 0; kk < 2; ++kk) \
        afrag[mrel][kk] = lds_frag(sA[bi], wr*128 + 3*32 + mrel*16 + ln15, kk*64 + kb16); \
    stage_chunk(Bm, n0, K, ko2, sB[bi], 2, wave, lane); \
    stage_chunk(Bm, n0, K, ko2, sB[bi], 3, wave, lane); \
    WAIT_VM(6); \
    BARRIER(); WAIT_LGKM0(); \
    __builtin_amdgcn_s_setprio(1); PH_MFMA(3); __builtin_amdgcn_s_setprio(0); \
    BARRIER(); \
} while (0)

// NT GEMM, 256^2 8-phase: C[M,N] = A[M,K] * Bm[N,K]^T, bf16 in, fp32 acc.
// EPI=0: Hout = bf16(silu(C)); EPI=1: fused bias + dynamic causal conv + silu.
template <int EPI>
__global__ __launch_bounds__(512, 2)
void gemm8p(const unsigned short* __restrict__ A,
            const unsigned short* __restrict__ Bm,
            int M, int N, int K,
            unsigned short* __restrict__ Hout,
            const float* __restrict__ bias,
            const float* __restrict__ Xf,
            float* __restrict__ Out) {
    __shared__ __align__(16) unsigned short sA[2][16384];  // 2 x 32KB
    __shared__ __align__(16) unsigned short sB[2][16384];  // 2 x 32KB

    const int tid  = threadIdx.x;
    const int wave = tid >> 6, lane = tid & 63;
    const int wr = wave >> 2, wc = wave & 3;        // 2M x 4N wave grid
    const int ln15 = lane & 15;
    const int kb16 = (lane >> 4) * 16;

    // T1: bijective XCD swizzle (nwg % 8 == 0 for all our grids)
    const int nwg = gridDim.x * gridDim.y;
    const int bid = blockIdx.y * gridDim.x + blockIdx.x;
    const int swz = (bid & 7) * (nwg >> 3) + (bid >> 3);
    const int bx = swz % gridDim.x, by = swz / gridDim.x;
    const int m0 = by * BM, n0 = bx * BN;

    const int nk = K >> 6;   // K-tiles

    f32x4 acc[8][4];
#pragma unroll
    for (int i = 0; i < 8; ++i)
#pragma unroll
        for (int j = 0; j < 4; ++j) acc[i][j] = (f32x4)0.0f;

    bf16x8 bfrag[4][2], afrag[2][2];

    // ---- prologue: stage K-tile 0 (4 units) + first 3 units of K-tile 1 ----
    stage_chunk(Bm, n0, K, 0, sB[0], 0, wave, lane);
    stage_chunk(Bm, n0, K, 0, sB[0], 1, wave, lane);   // U_B1(0)
    stage_chunk(A,  m0, K, 0, sA[0], 0, wave, lane);
    stage_chunk(A,  m0, K, 0, sA[0], 2, wave, lane);   // U_A1(0)
    stage_chunk(Bm, n0, K, 0, sB[0], 2, wave, lane);
    stage_chunk(Bm, n0, K, 0, sB[0], 3, wave, lane);   // U_B2(0)
    stage_chunk(A,  m0, K, 0, sA[0], 1, wave, lane);
    stage_chunk(A,  m0, K, 0, sA[0], 3, wave, lane);   // U_A2(0)
    WAIT_VM(4);
    stage_chunk(Bm, n0, K, BKT, sB[1], 0, wave, lane);
    stage_chunk(Bm, n0, K, BKT, sB[1], 1, wave, lane); // U_B1(1)
    stage_chunk(A,  m0, K, BKT, sA[1], 0, wave, lane);
    stage_chunk(A,  m0, K, BKT, sA[1], 2, wave, lane); // U_A1(1)
    stage_chunk(Bm, n0, K, BKT, sB[1], 2, wave, lane);
    stage_chunk(Bm, n0, K, BKT, sB[1], 3, wave, lane); // U_B2(1)
    WAIT_VM(6);
    BARRIER();

    // ---- main loop: 2 K-tiles (8 phases) per iteration ----
    for (int it = 0; it < (nk >> 1); ++it) {
        const int j = it << 1;
        KTILE(0, j);
        KTILE(1, j + 1);
    }
    asm volatile("s_waitcnt vmcnt(0)" ::: "memory");

    // ---- epilogue ----
    if (EPI == 0) {
#pragma unroll
        for (int mf = 0; mf < 8; ++mf) {
            int rowb = m0 + wr * 128 + mf * 16 + (lane >> 4) * 4;
#pragma unroll
            for (int nf = 0; nf < 4; ++nf) {
                int col = n0 + wc * 64 + nf * 16 + ln15;
#pragma unroll
                for (int r = 0; r < 4; ++r) {
                    Hout[(size_t)(rowb + r) * N + col] = f2bf(silu_f(acc[mf][nf][r]));
                }
            }
        }
    } else {
        // k = C + bias; out[b,t,d] = silu(sum_w x[b,t-3+w,d] * k[t, d*4+w])
        // col -> (d = col>>2, w = col&3); 4-lane butterfly sums over w.
#pragma unroll
        for (int mf = 0; mf < 8; ++mf) {
            int rowb = m0 + wr * 128 + mf * 16 + (lane >> 4) * 4;
#pragma unroll
            for (int nf = 0; nf < 4; ++nf) {
                int col = n0 + wc * 64 + nf * 16 + ln15;
                int d = col >> 2;
                int w = col & 3;
                float bv = bias[col];
#pragma unroll
                for (int r = 0; r < 4; ++r) {
                    int row = rowb + r;
                    int b = row >> 12;            // T = 4096
                    int t = row & (T_DIM - 1);
                    float v = acc[mf][nf][r] + bv;
                    int ts = t - (W_K - 1) + w;   // causal window
                    float xv = (ts >= 0) ? Xf[((size_t)b * T_DIM + ts) * D_DIM + d]
                                         : 0.0f;
                    float p = v * xv;
                    p += __shfl_xor(p, 1);
                    p += __shfl_xor(p, 2);
                    if ((lane & 3) == 0) {
                        Out[((size_t)b * T_DIM + t) * D_DIM + d] = silu_f(p);
                    }
                }
            }
        }
    }
}

extern "C" void kernel_launch(void* const* d_in, const int* in_sizes, int n_in,
                              void* d_out, int out_size, void* d_ws, size_t ws_size,
                              hipStream_t stream) {
    const float* x    = (const float*)d_in[0];  // [B,T,D]
    const float* w1   = (const float*)d_in[1];  // [H,D]
    const float* w2w  = (const float*)d_in[2];  // [D*W,H]
    const float* w2b  = (const float*)d_in[3];  // [D*W]
    float* out = (float*)d_out;

    // Workspace: ws0 = xb [M,D] bf16 (later reused for w2wb [N2,H] bf16),
    //            ws1 = w1b [H,D] bf16, ws2 = hb [M,H] bf16.
    unsigned short* ws0 = (unsigned short*)d_ws;
    unsigned short* ws1 = ws0 + (size_t)M_DIM * D_DIM;
    unsigned short* ws2 = ws1 + (size_t)H_DIM * D_DIM;

    const int CT = 256;
    {
        int n4 = (M_DIM * D_DIM) / 4;
        cvt_f32_to_bf16<<<(n4 + CT - 1) / CT, CT, 0, stream>>>(x, ws0, n4);
    }
    {
        int n4 = (H_DIM * D_DIM) / 4;
        cvt_f32_to_bf16<<<(n4 + CT - 1) / CT, CT, 0, stream>>>(w1, ws1, n4);
    }
    // GEMM1: hb = silu(xb @ w1b^T)  [8192, 2048]
    gemm8p<0><<<dim3(H_DIM / BN, M_DIM / BM), 512, 0, stream>>>(
        ws0, ws1, M_DIM, H_DIM, D_DIM, ws2, nullptr, nullptr, nullptr);
    // convert w2_w into ws0 (xb now dead)
    {
        int n4 = (N2_DIM * H_DIM) / 4;
        cvt_f32_to_bf16<<<(n4 + CT - 1) / CT, CT, 0, stream>>>(w2w, ws0, n4);
    }
    // GEMM2 + fused bias/conv/silu -> out
    gemm8p<1><<<dim3(N2_DIM / BN, M_DIM / BM), 512, 0, stream>>>(
        ws2, ws0, M_DIM, N2_DIM, H_DIM, nullptr, w2b, x, out);
}

// Round 3
// 497.757 us; speedup vs baseline: 1.0516x; 1.0516x over previous
//
#include <hip/hip_runtime.h>
#include <hip/hip_bf16.h>
#include <math.h>

// Problem constants (B=2, T=4096, D=2048, H=2048, W=4)
#define B_DIM 2
#define T_DIM 4096
#define D_DIM 2048
#define H_DIM 2048
#define W_K   4
#define M_DIM (B_DIM * T_DIM)   // 8192 tokens
#define N2_DIM (D_DIM * W_K)    // 8192

typedef __bf16 bf16x8 __attribute__((ext_vector_type(8)));
typedef float  f32x4  __attribute__((ext_vector_type(4)));

// 256x256 tile, K-tile 64, 8 waves (2M x 4N), 512 threads
#define BM 256
#define BN 256
#define BKT 64

__device__ __forceinline__ unsigned short f2bf(float f) {
    unsigned int u = __float_as_uint(f);
    unsigned int r = (u + 0x7FFFu + ((u >> 16) & 1u)) >> 16;  // RNE
    return (unsigned short)r;
}

__device__ __forceinline__ float silu_f(float v) {
    return v / (1.0f + __expf(-v));
}

__global__ void cvt_f32_to_bf16(const float* __restrict__ in,
                                unsigned short* __restrict__ out, int n4) {
    int i = blockIdx.x * blockDim.x + threadIdx.x;
    if (i >= n4) return;
    float4 v = reinterpret_cast<const float4*>(in)[i];
    ushort4 o;
    o.x = f2bf(v.x); o.y = f2bf(v.y); o.z = f2bf(v.z); o.w = f2bf(v.w);
    reinterpret_cast<ushort4*>(out)[i] = o;
}

// LDS tile: [256 rows][64 bf16] = 128 B/row, XOR-swizzled:
//   phys = row*128 + (colbyte ^ ((row&7)<<4))
// Derivation (G4): fragment ds_read_b128 puts 16 lanes at the same colbyte
// with rows base+0..15; XOR of (row&7) into byte bits [4:6] spreads 8 rows
// over all 8 16B slots (= 32 banks); the 2-way repeat (rows 8..15) is free.
__device__ __forceinline__ bf16x8 lds_frag(const unsigned short* buf, int r, int kbyte) {
    int lin = r * 128 + (kbyte ^ ((r & 7) << 4));
    return *reinterpret_cast<const bf16x8*>(reinterpret_cast<const char*>(buf) + lin);
}

// Stage one 8KB chunk (64 rows x 64 cols bf16) of a K-tile into LDS.
// LDS dest is linear (global_load_lds: wave-uniform base + lane*16); the
// swizzle is applied by INVERSE-swizzling the global source address
// (rule #21: both-sides-or-neither; XOR swizzle is an involution).
__device__ __forceinline__ void stage_chunk(const unsigned short* __restrict__ G,
                                            int row0, int K, int ko,
                                            unsigned short* lbuf, int chunk,
                                            int wave, int lane) {
    int db  = chunk * 8192 + wave * 1024 + lane * 16;   // physical LDS byte
    int row = db >> 7;                                   // tile row 0..255
    int cb  = (db & 127) ^ ((row & 7) << 4);             // logical col byte
    const unsigned short* src = &G[(size_t)(row0 + row) * K + ko + (cb >> 1)];
    __builtin_amdgcn_global_load_lds(
        (const __attribute__((address_space(1))) void*)src,
        (__attribute__((address_space(3))) void*)(reinterpret_cast<char*>(lbuf) + db),
        16, 0, 0);
}

#define BARRIER()    __builtin_amdgcn_s_barrier()
#define WAIT_LGKM0() asm volatile("s_waitcnt lgkmcnt(0)" ::: "memory")
#define WAIT_VM(N)   asm volatile("s_waitcnt vmcnt(" #N ")" ::: "memory")

// 16 MFMA of one phase: M-group mg (2 Mfrags) x 4 Nfrags x 2 K-steps.
#define PH_MFMA(mg) \
    _Pragma("unroll") for (int kk = 0; kk < 2; ++kk) \
    _Pragma("unroll") for (int mrel = 0; mrel < 2; ++mrel) \
    _Pragma("unroll") for (int nf = 0; nf < 4; ++nf) \
        acc[(mg)*2 + mrel][nf] = __builtin_amdgcn_mfma_f32_16x16x32_bf16( \
            afrag[mrel][kk], bfrag[nf][kk], acc[(mg)*2 + mrel][nf], 0, 0, 0)

// One K-tile = 4 phases. Stage schedule (clobber-safe by last-read phase):
//   ph1: U_A2(j+1) -> other buf, A chunks 1,3   (A mg{2,3} of j-1 done at j-1 ph4)
//   ph2: U_B1(j+2) -> this buf,  B chunks 0,1   (B fully read at ph1)
//   ph3: U_A1(j+2) -> this buf,  A chunks 0,2   (A mg{0,1} read at ph1,ph2)
//   ph4: U_B2(j+2) -> this buf,  B chunks 2,3 ; vmcnt(6) = 3 half-tiles in flight
#define KTILE(bi, jj) do { \
    int j1 = (jj) + 1; if (j1 >= nk) j1 -= nk; \
    int j2 = (jj) + 2; if (j2 >= nk) j2 -= nk; \
    const int ko1 = j1 * BKT, ko2 = j2 * BKT; \
    /* ---- phase 1 (mg=0): read all B (8) + A mg0 (4) = 12 ds_read_b128 ---- */ \
    _Pragma("unroll") for (int nf = 0; nf < 4; ++nf) \
    _Pragma("unroll") for (int kk = 0; kk < 2; ++kk) \
        bfrag[nf][kk] = lds_frag(sB[bi], wc*64 + nf*16 + ln15, kk*64 + kb16); \
    _Pragma("unroll") for (int mrel = 0; mrel < 2; ++mrel) \
    _Pragma("unroll") for (int kk = 0; kk < 2; ++kk) \
        afrag[mrel][kk] = lds_frag(sA[bi], wr*128 + 0*32 + mrel*16 + ln15, kk*64 + kb16); \
    stage_chunk(A, m0, K, ko1, sA[(bi)^1], 1, wave, lane); \
    stage_chunk(A, m0, K, ko1, sA[(bi)^1], 3, wave, lane); \
    BARRIER(); WAIT_LGKM0(); \
    __builtin_amdgcn_s_setprio(1); PH_MFMA(0); __builtin_amdgcn_s_setprio(0); \
    BARRIER(); \
    /* ---- phase 2 (mg=1) ---- */ \
    _Pragma("unroll") for (int mrel = 0; mrel < 2; ++mrel) \
    _Pragma("unroll") for (int kk = 0; kk < 2; ++kk) \
        afrag[mrel][kk] = lds_frag(sA[bi], wr*128 + 1*32 + mrel*16 + ln15, kk*64 + kb16); \
    stage_chunk(Bm, n0, K, ko2, sB[bi], 0, wave, lane); \
    stage_chunk(Bm, n0, K, ko2, sB[bi], 1, wave, lane); \
    BARRIER(); WAIT_LGKM0(); \
    __builtin_amdgcn_s_setprio(1); PH_MFMA(1); __builtin_amdgcn_s_setprio(0); \
    BARRIER(); \
    /* ---- phase 3 (mg=2) ---- */ \
    _Pragma("unroll") for (int mrel = 0; mrel < 2; ++mrel) \
    _Pragma("unroll") for (int kk = 0; kk < 2; ++kk) \
        afrag[mrel][kk] = lds_frag(sA[bi], wr*128 + 2*32 + mrel*16 + ln15, kk*64 + kb16); \
    stage_chunk(A, m0, K, ko2, sA[bi], 0, wave, lane); \
    stage_chunk(A, m0, K, ko2, sA[bi], 2, wave, lane); \
    BARRIER(); WAIT_LGKM0(); \
    __builtin_amdgcn_s_setprio(1); PH_MFMA(2); __builtin_amdgcn_s_setprio(0); \
    BARRIER(); \
    /* ---- phase 4 (mg=3): counted vmcnt, never 0 in main loop ---- */ \
    _Pragma("unroll") for (int mrel = 0; mrel < 2; ++mrel) \
    _Pragma("unroll") for (int kk = 0; kk < 2; ++kk) \
        afrag[mrel][kk] = lds_frag(sA[bi], wr*128 + 3*32 + mrel*16 + ln15, kk*64 + kb16); \
    stage_chunk(Bm, n0, K, ko2, sB[bi], 2, wave, lane); \
    stage_chunk(Bm, n0, K, ko2, sB[bi], 3, wave, lane); \
    WAIT_VM(6); \
    BARRIER(); WAIT_LGKM0(); \
    __builtin_amdgcn_s_setprio(1); PH_MFMA(3); __builtin_amdgcn_s_setprio(0); \
    BARRIER(); \
} while (0)

// NT GEMM, 256^2 8-phase: C[M,N] = A[M,K] * Bm[N,K]^T, bf16 in, fp32 acc.
// EPI=0: Hout = bf16(silu(C)); EPI=1: fused bias + dynamic causal conv + silu.
template <int EPI>
__global__ __launch_bounds__(512, 2)
void gemm8p(const unsigned short* __restrict__ A,
            const unsigned short* __restrict__ Bm,
            int M, int N, int K,
            unsigned short* __restrict__ Hout,
             const float* __restrict__ bias,
            const float* __restrict__ Xf,
            float* __restrict__ Out) {
    __shared__ __align__(16) unsigned short sA[2][16384];  // 2 x 32KB
    __shared__ __align__(16) unsigned short sB[2][16384];  // 2 x 32KB

    const int tid  = threadIdx.x;
    const int wave = tid >> 6, lane = tid & 63;
    const int wr = wave >> 2, wc = wave & 3;        // 2M x 4N wave grid
    const int ln15 = lane & 15;
    const int kb16 = (lane >> 4) * 16;

    // T1: bijective XCD swizzle (nwg % 8 == 0 for all our grids)
    const int nwg = gridDim.x * gridDim.y;
    const int bid = blockIdx.y * gridDim.x + blockIdx.x;
    const int swz = (bid & 7) * (nwg >> 3) + (bid >> 3);
    const int bx = swz % gridDim.x, by = swz / gridDim.x;
    const int m0 = by * BM, n0 = bx * BN;

    const int nk = K >> 6;   // K-tiles

    f32x4 acc[8][4];
#pragma unroll
    for (int i = 0; i < 8; ++i)
#pragma unroll
        for (int j = 0; j < 4; ++j) acc[i][j] = (f32x4)0.0f;

    bf16x8 bfrag[4][2], afrag[2][2];

    // ---- prologue: stage K-tile 0 (4 units) + first 3 units of K-tile 1 ----
    stage_chunk(Bm, n0, K, 0, sB[0], 0, wave, lane);
    stage_chunk(Bm, n0, K, 0, sB[0], 1, wave, lane);   // U_B1(0)
    stage_chunk(A,  m0, K, 0, sA[0], 0, wave, lane);
    stage_chunk(A,  m0, K, 0, sA[0], 2, wave, lane);   // U_A1(0)
    stage_chunk(Bm, n0, K, 0, sB[0], 2, wave, lane);
    stage_chunk(Bm, n0, K, 0, sB[0], 3, wave, lane);   // U_B2(0)
    stage_chunk(A,  m0, K, 0, sA[0], 1, wave, lane);
    stage_chunk(A,  m0, K, 0, sA[0], 3, wave, lane);   // U_A2(0)
    WAIT_VM(4);
    stage_chunk(Bm, n0, K, BKT, sB[1], 0, wave, lane);
    stage_chunk(Bm, n0, K, BKT, sB[1], 1, wave, lane); // U_B1(1)
    stage_chunk(A,  m0, K, BKT, sA[1], 0, wave, lane);
    stage_chunk(A,  m0, K, BKT, sA[1], 2, wave, lane); // U_A1(1)
    stage_chunk(Bm, n0, K, BKT, sB[1], 2, wave, lane);
    stage_chunk(Bm, n0, K, BKT, sB[1], 3, wave, lane); // U_B2(1)
    WAIT_VM(6);
    BARRIER();

    // ---- main loop: 2 K-tiles (8 phases) per iteration ----
    for (int it = 0; it < (nk >> 1); ++it) {
        const int j = it << 1;
        KTILE(0, j);
        KTILE(1, j + 1);
    }
    asm volatile("s_waitcnt vmcnt(0)" ::: "memory");

    // ---- epilogue ----
    if (EPI == 0) {
#pragma unroll
        for (int mf = 0; mf < 8; ++mf) {
            int rowb = m0 + wr * 128 + mf * 16 + (lane >> 4) * 4;
#pragma unroll
            for (int nf = 0; nf < 4; ++nf) {
                int col = n0 + wc * 64 + nf * 16 + ln15;
#pragma unroll
                for (int r = 0; r < 4; ++r) {
                    Hout[(size_t)(rowb + r) * N + col] = f2bf(silu_f(acc[mf][nf][r]));
                }
            }
        }
    } else {
        // k = C + bias; out[b,t,d] = silu(sum_w x[b,t-3+w,d] * k[t, d*4+w])
        // col -> (d = col>>2, w = col&3); 4-lane butterfly sums over w.
#pragma unroll
        for (int mf = 0; mf < 8; ++mf) {
            int rowb = m0 + wr * 128 + mf * 16 + (lane >> 4) * 4;
#pragma unroll
            for (int nf = 0; nf < 4; ++nf) {
                int col = n0 + wc * 64 + nf * 16 + ln15;
                int d = col >> 2;
                int w = col & 3;
                float bv = bias[col];
#pragma unroll
                for (int r = 0; r < 4; ++r) {
                    int row = rowb + r;
                    int b = row >> 12;            // T = 4096
                    int t = row & (T_DIM - 1);
                    float v = acc[mf][nf][r] + bv;
                    int ts = t - (W_K - 1) + w;   // causal window
                    float xv = (ts >= 0) ? Xf[((size_t)b * T_DIM + ts) * D_DIM + d]
                                         : 0.0f;
                    float p = v * xv;
                    p += __shfl_xor(p, 1);
                    p += __shfl_xor(p, 2);
                    if ((lane & 3) == 0) {
                        Out[((size_t)b * T_DIM + t) * D_DIM + d] = silu_f(p);
                    }
                }
            }
        }
    }
}

extern "C" void kernel_launch(void* const* d_in, const int* in_sizes, int n_in,
                              void* d_out, int out_size, void* d_ws, size_t ws_size,
                              hipStream_t stream) {
    const float* x    = (const float*)d_in[0];  // [B,T,D]
    const float* w1   = (const float*)d_in[1];  // [H,D]
    const float* w2w  = (const float*)d_in[2];  // [D*W,H]
    const float* w2b  = (const float*)d_in[3];  // [D*W]
    float* out = (float*)d_out;

    // Workspace: ws0 = xb [M,D] bf16 (later reused for w2wb [N2,H] bf16),
    //            ws1 = w1b [H,D] bf16, ws2 = hb [M,H] bf16.
    unsigned short* ws0 = (unsigned short*)d_ws;
    unsigned short* ws1 = ws0 + (size_t)M_DIM * D_DIM;
    unsigned short* ws2 = ws1 + (size_t)H_DIM * D_DIM;

    const int CT = 256;
    {
        int n4 = (M_DIM * D_DIM) / 4;
        cvt_f32_to_bf16<<<(n4 + CT - 1) / CT, CT, 0, stream>>>(x, ws0, n4);
    }
    {
        int n4 = (H_DIM * D_DIM) / 4;
        cvt_f32_to_bf16<<<(n4 + CT - 1) / CT, CT, 0, stream>>>(w1, ws1, n4);
    }
    // GEMM1: hb = silu(xb @ w1b^T)  [8192, 2048]
    gemm8p<0><<<dim3(H_DIM / BN, M_DIM / BM), 512, 0, stream>>>(
        ws0, ws1, M_DIM, H_DIM, D_DIM, ws2, nullptr, nullptr, nullptr);
    // convert w2_w into ws0 (xb now dead)
    {
        int n4 = (N2_DIM * H_DIM) / 4;
        cvt_f32_to_bf16<<<(n4 + CT - 1) / CT, CT, 0, stream>>>(w2w, ws0, n4);
    }
    // GEMM2 + fused bias/conv/silu -> out
    gemm8p<1><<<dim3(N2_DIM / BN, M_DIM / BM), 512, 0, stream>>>(
        ws2, ws0, M_DIM, N2_DIM, H_DIM, nullptr, w2b, x, out);
}

// Round 4
// 430.157 us; speedup vs baseline: 1.2169x; 1.1572x over previous
//
#include <hip/hip_runtime.h>
#include <hip/hip_bf16.h>
#include <math.h>

// Problem constants (B=2, T=4096, D=2048, H=2048, W=4)
#define B_DIM 2
#define T_DIM 4096
#define D_DIM 2048
#define H_DIM 2048
#define W_K   4
#define M_DIM (B_DIM * T_DIM)   // 8192 tokens
#define N2_DIM (D_DIM * W_K)    // 8192

typedef __bf16 bf16x8 __attribute__((ext_vector_type(8)));
typedef float  f32x4  __attribute__((ext_vector_type(4)));

// 256x256 tile, K-tile 32, quad-buffered rotation, 8 waves (2M x 4N)
#define BM 256
#define BN 256
#define BKT 32
// LDS: A tiles at smem[slot*8192], B tiles at smem[32768 + slot*8192] (ushorts)
#define XW_STRIDE 68   // f32 stride for epilogue x-window (2-way-free banks)

__device__ __forceinline__ unsigned short f2bf(float f) {
    unsigned int u = __float_as_uint(f);
    unsigned int r = (u + 0x7FFFu + ((u >> 16) & 1u)) >> 16;  // RNE
    return (unsigned short)r;
}

__device__ __forceinline__ float silu_f(float v) {
    return v / (1.0f + __expf(-v));
}

__global__ void cvt_f32_to_bf16(const float* __restrict__ in,
                                unsigned short* __restrict__ out, int n4) {
    int i = blockIdx.x * blockDim.x + threadIdx.x;
    if (i >= n4) return;
    float4 v = reinterpret_cast<const float4*>(in)[i];
    ushort4 o;
    o.x = f2bf(v.x); o.y = f2bf(v.y); o.z = f2bf(v.z); o.w = f2bf(v.w);
    reinterpret_cast<ushort4*>(out)[i] = o;
}

// LDS tile: [256 rows][32 bf16] = 64 B/row, XOR swizzle:
//   phys = r*64 + (colbyte ^ (((r>>1)&3)<<4))
// ds_read_b128: 16 lanes share colbyte with rows r..r+15 -> (r parity, slot)
// gives 8 distinct bank-quads for 16 lanes = exact 2-way aliasing (free, m136).
__device__ __forceinline__ bf16x8 lds_frag(const unsigned short* buf, int r, int kb) {
    int lin = r * 64 + (kb ^ (((r >> 1) & 3) << 4));
    return *reinterpret_cast<const bf16x8*>(reinterpret_cast<const char*>(buf) + lin);
}

#define BARRIER()    __builtin_amdgcn_s_barrier()
#define WAIT_LGKM0() asm volatile("s_waitcnt lgkmcnt(0)" ::: "memory")
#define WAIT_VM(N)   asm volatile("s_waitcnt vmcnt(" #N ")" ::: "memory")

// Stage one 8KB chunk (128 rows x 32 cols bf16) of a K-tile into LDS.
// Dest is wave-uniform base (HW scatters lane*16B); swizzle applied by
// inverse-permuting the per-lane GLOBAL source (rule #21, XOR involution).
// off0/off1 are per-thread element offsets (row*K + swizzled colbyte/2).
#define STAGE(basePtr, ko, dstUshort, chunk) \
    __builtin_amdgcn_global_load_lds( \
        (const __attribute__((address_space(1))) void*)((basePtr) + ((chunk) ? off1 : off0) + (ko)), \
        (__attribute__((address_space(3))) void*)(reinterpret_cast<char*>(dstUshort) + ((chunk) << 13) + (wave << 10)), \
        16, 0, 0)

// 16 MFMA of one phase: 4 Mfrags x 4 Nfrags, K=32.
#define PH_MFMA(mbase, AF) \
    _Pragma("unroll") for (int mf = 0; mf < 4; ++mf) \
    _Pragma("unroll") for (int nf = 0; nf < 4; ++nf) \
        acc[(mbase) + mf][nf] = __builtin_amdgcn_mfma_f32_16x16x32_bf16( \
            AF[mf], bfrag[nf], acc[(mbase) + mf][nf], 0, 0, 0)

// One K-tile = 2 phases. Stage tile j+3 (buf (j+3)&3 == buf of consumed tile
// j-1). vmcnt(8) once per tile retires tile j+1 (issued during tile j-2):
// ~5 phases of latency cover; 8-12 loads in flight steady-state.
#define KTILE(slot, jj) do { \
    int j3 = (jj) + 3; if (j3 >= nk) j3 -= nk; \
    const int ko3 = j3 << 5; \
    const unsigned short* tA = smem + (slot) * 8192; \
    const unsigned short* tB = smem + 32768 + (slot) * 8192; \
    unsigned short* dA = smem + (((slot) + 3) & 3) * 8192; \
    unsigned short* dB = smem + 32768 + (((slot) + 3) & 3) * 8192; \
    /* ---- phase 1: read B(all) + A mf0-3 (8 ds_read_b128); stage B(j+3) ---- */ \
    _Pragma("unroll") for (int nf = 0; nf < 4; ++nf) \
        bfrag[nf] = lds_frag(tB, wc * 64 + nf * 16 + ln15, kb16); \
    _Pragma("unroll") for (int mf = 0; mf < 4; ++mf) \
        afrag[mf] = lds_frag(tA, wr * 128 + mf * 16 + ln15, kb16); \
    STAGE(baseB, ko3, dB, 0); \
    STAGE(baseB, ko3, dB, 1); \
    BARRIER(); WAIT_LGKM0(); \
    __builtin_amdgcn_s_setprio(1); PH_MFMA(0, afrag); __builtin_amdgcn_s_setprio(0); \
    BARRIER(); \
    /* ---- phase 2: read A mf4-7; stage A(j+3); counted vmcnt(8) ---- */ \
    _Pragma("unroll") for (int mf = 0; mf < 4; ++mf) \
        afrag2[mf] = lds_frag(tA, wr * 128 + (4 + mf) * 16 + ln15, kb16); \
    STAGE(baseA, ko3, dA, 0); \
    STAGE(baseA, ko3, dA, 1); \
    WAIT_VM(8); \
    BARRIER(); WAIT_LGKM0(); \
    __builtin_amdgcn_s_setprio(1); PH_MFMA(4, afrag2); __builtin_amdgcn_s_setprio(0); \
    BARRIER(); \
} while (0)

// NT GEMM, 256^2 quad-buffered 2-phase/K32: C = A[M,K] * Bm[N,K]^T.
// EPI=0: Hout = bf16(silu(C)); EPI=1: fused bias + dynamic causal conv + silu
// with LDS-staged x-window.
template <int EPI>
__global__ __launch_bounds__(512, 2)
void gemm8p(const unsigned short* __restrict__ A,
            const unsigned short* __restrict__ Bm,
            int M, int N, int K,
            unsigned short* __restrict__ Hout,
            const float* __restrict__ bias,
            const float* __restrict__ Xf,
            float* __restrict__ Out) {
    __shared__ __align__(16) unsigned short smem[65536];  // 128 KB

    const int tid  = threadIdx.x;
    const int wave = tid >> 6, lane = tid & 63;
    const int wr = wave >> 2, wc = wave & 3;        // 2M x 4N wave grid
    const int ln15 = lane & 15;
    const int kb16 = (lane >> 4) * 16;              // 16B k-slot in 64B row

    // T1: bijective XCD swizzle (nwg % 8 == 0 for all our grids)
    const int nwg = gridDim.x * gridDim.y;
    const int bid = blockIdx.y * gridDim.x + blockIdx.x;
    const int swz = (bid & 7) * (nwg >> 3) + (bid >> 3);
    const int bx = swz % gridDim.x, by = swz / gridDim.x;
    const int m0 = by * BM, n0 = bx * BN;

    const int nk = K >> 5;   // K-tiles of 32

    // Per-thread staging offsets (thread-constant): chunk c covers rows
    // c*128 + wave*16 + lane/4; within-row 16B slot = lane&3, inverse-swizzled.
    const int r0 = (wave << 4) + (lane >> 2);
    const int r1 = 128 + r0;
    const int cb0 = ((lane & 3) << 4) ^ (((r0 >> 1) & 3) << 4);
    const int cb1 = ((lane & 3) << 4) ^ (((r1 >> 1) & 3) << 4);
    const size_t off0 = (size_t)r0 * K + (cb0 >> 1);
    const size_t off1 = (size_t)r1 * K + (cb1 >> 1);
    const unsigned short* baseA = A + (size_t)m0 * K;
    const unsigned short* baseB = Bm + (size_t)n0 * K;

    f32x4 acc[8][4];
#pragma unroll
    for (int i = 0; i < 8; ++i)
#pragma unroll
        for (int j = 0; j < 4; ++j) acc[i][j] = (f32x4)0.0f;

    bf16x8 bfrag[4], afrag[4], afrag2[4];

    // ---- prologue: stage tiles 0,1,2 (tile t's 4 loads contiguous) ----
#pragma unroll
    for (int t = 0; t < 3; ++t) {
        const int ko = t << 5;
        unsigned short* dA = smem + t * 8192;
        unsigned short* dB = smem + 32768 + t * 8192;
        STAGE(baseB, ko, dB, 0);
        STAGE(baseB, ko, dB, 1);
        STAGE(baseA, ko, dA, 0);
        STAGE(baseA, ko, dA, 1);
    }
    WAIT_VM(8);   // tile 0 landed; tiles 1,2 in flight
    BARRIER();

    // ---- main loop ----
    for (int it = 0; it < (nk >> 2); ++it) {
        const int j = it << 2;
        KTILE(0, j);
        KTILE(1, j + 1);
        KTILE(2, j + 2);
        KTILE(3, j + 3);
    }
    asm volatile("s_waitcnt vmcnt(0)" ::: "memory");  // drain wrapped stages
    BARRIER();

    // ---- epilogue ----
    if (EPI == 0) {
#pragma unroll
        for (int mf = 0; mf < 8; ++mf) {
            int rowb = m0 + wr * 128 + mf * 16 + (lane >> 4) * 4;
#pragma unroll
            for (int nf = 0; nf < 4; ++nf) {
                int col = n0 + wc * 64 + nf * 16 + ln15;
#pragma unroll
                for (int r = 0; r < 4; ++r) {
                    Hout[(size_t)(rowb + r) * N + col] = f2bf(silu_f(acc[mf][nf][r]));
                }
            }
        }
    } else {
        // Stage x-window into LDS: rows ts = t0-3 .. t0+255 (259), 64 d cols.
        const int t0 = m0 & (T_DIM - 1);
        const int bidx = m0 >> 12;
        const int dbase = n0 >> 2;
        float* Xw = reinterpret_cast<float*>(smem);   // [259][XW_STRIDE]
        for (int idx = tid; idx < 259 * 16; idx += 512) {
            int rw = idx >> 4, q = (idx & 15) << 2;
            int ts = t0 - 3 + rw;
            float4 v = make_float4(0.f, 0.f, 0.f, 0.f);
            if (ts >= 0)
                v = *reinterpret_cast<const float4*>(
                    &Xf[((size_t)bidx * T_DIM + ts) * D_DIM + dbase + q]);
            float* p = &Xw[rw * XW_STRIDE + q];
            p[0] = v.x; p[1] = v.y; p[2] = v.z; p[3] = v.w;
        }
        __syncthreads();

        // k = C + bias; out[b,t,d] = silu(sum_w x[b,t-3+w,d] * k[t, d*4+w])
        // col -> (d = col>>2, w = col&3); 4-lane butterfly sums over w.
        const int dl = wc * 16 + (ln15 >> 2);   // + nf*4 below
        const int w = lane & 3;
#pragma unroll
        for (int mf = 0; mf < 8; ++mf) {
            int lrow0 = wr * 128 + mf * 16 + (lane >> 4) * 4;
#pragma unroll
            for (int nf = 0; nf < 4; ++nf) {
                int col = n0 + wc * 64 + nf * 16 + ln15;
                int d = col >> 2;
                float bv = bias[col];
#pragma unroll
                for (int r = 0; r < 4; ++r) {
                    int lrow = lrow0 + r;
                    float v = acc[mf][nf][r] + bv;
                    float xv = Xw[(lrow + w) * XW_STRIDE + dl + nf * 4];
                    float p = v * xv;
                    p += __shfl_xor(p, 1);
                    p += __shfl_xor(p, 2);
                    if ((lane & 3) == 0) {
                        Out[((size_t)bidx * T_DIM + (t0 + lrow)) * D_DIM + d] = silu_f(p);
                    }
                }
            }
        }
    }
}

extern "C" void kernel_launch(void* const* d_in, const int* in_sizes, int n_in,
                              void* d_out, int out_size, void* d_ws, size_t ws_size,
                              hipStream_t stream) {
    const float* x    = (const float*)d_in[0];  // [B,T,D]
    const float* w1   = (const float*)d_in[1];  // [H,D]
    const float* w2w  = (const float*)d_in[2];  // [D*W,H]
    const float* w2b  = (const float*)d_in[3];  // [D*W]
    float* out = (float*)d_out;

    // Workspace: ws0 = xb [M,D] bf16 (later reused for w2wb [N2,H] bf16),
    //            ws1 = w1b [H,D] bf16, ws2 = hb [M,H] bf16.
    unsigned short* ws0 = (unsigned short*)d_ws;
    unsigned short* ws1 = ws0 + (size_t)M_DIM * D_DIM;
    unsigned short* ws2 = ws1 + (size_t)H_DIM * D_DIM;

    const int CT = 256;
    {
        int n4 = (M_DIM * D_DIM) / 4;
        cvt_f32_to_bf16<<<(n4 + CT - 1) / CT, CT, 0, stream>>>(x, ws0, n4);
    }
    {
        int n4 = (H_DIM * D_DIM) / 4;
        cvt_f32_to_bf16<<<(n4 + CT - 1) / CT, CT, 0, stream>>>(w1, ws1, n4);
    }
    // GEMM1: hb = silu(xb @ w1b^T)  [8192, 2048]
    gemm8p<0><<<dim3(H_DIM / BN, M_DIM / BM), 512, 0, stream>>>(
        ws0, ws1, M_DIM, H_DIM, D_DIM, ws2, nullptr, nullptr, nullptr);
    // convert w2_w into ws0 (xb now dead)
    {
        int n4 = (N2_DIM * H_DIM) / 4;
        cvt_f32_to_bf16<<<(n4 + CT - 1) / CT, CT, 0, stream>>>(w2w, ws0, n4);
    }
    // GEMM2 + fused bias/conv/silu -> out
    gemm8p<1><<<dim3(N2_DIM / BN, M_DIM / BM), 512, 0, stream>>>(
        ws2, ws0, M_DIM, N2_DIM, H_DIM, nullptr, w2b, x, out);
}

// Round 5
// 412.409 us; speedup vs baseline: 1.2693x; 1.0430x over previous
//
#include <hip/hip_runtime.h>
#include <hip/hip_bf16.h>
#include <math.h>

// Problem constants (B=2, T=4096, D=2048, H=2048, W=4)
#define B_DIM 2
#define T_DIM 4096
#define D_DIM 2048
#define H_DIM 2048
#define W_K   4
#define M_DIM (B_DIM * T_DIM)   // 8192 tokens
#define N2_DIM (D_DIM * W_K)    // 8192

typedef __bf16 bf16x8 __attribute__((ext_vector_type(8)));
typedef float  f32x4  __attribute__((ext_vector_type(4)));

// 256x256 tile, K-tile 32, quad-buffered rotation, 8 waves (2M x 4N)
#define BM 256
#define BN 256
#define BKT 32
#define XW_STRIDE 68   // f32 stride for epilogue x-window (2-way-free banks)

__device__ __forceinline__ unsigned short f2bf(float f) {
    unsigned int u = __float_as_uint(f);
    unsigned int r = (u + 0x7FFFu + ((u >> 16) & 1u)) >> 16;  // RNE
    return (unsigned short)r;
}

__device__ __forceinline__ float silu_f(float v) {
    return v / (1.0f + __expf(-v));
}

__global__ void cvt_f32_to_bf16(const float* __restrict__ in,
                                unsigned short* __restrict__ out, int n4) {
    int i = blockIdx.x * blockDim.x + threadIdx.x;
    if (i >= n4) return;
    float4 v = reinterpret_cast<const float4*>(in)[i];
    ushort4 o;
    o.x = f2bf(v.x); o.y = f2bf(v.y); o.z = f2bf(v.z); o.w = f2bf(v.w);
    reinterpret_cast<ushort4*>(out)[i] = o;
}

// LDS tile: [256 rows][32 bf16] = 64 B/row, XOR swizzle:
//   phys = r*64 + (colbyte ^ (((r>>1)&3)<<4))
// ds_read_b128: 16 lanes share colbyte with rows r..r+15 -> exact 2-way bank
// aliasing (free, m136).
__device__ __forceinline__ bf16x8 lds_frag(const unsigned short* buf, int r, int kb) {
    int lin = r * 64 + (kb ^ (((r >> 1) & 3) << 4));
    return *reinterpret_cast<const bf16x8*>(reinterpret_cast<const char*>(buf) + lin);
}

#define BARRIER()    __builtin_amdgcn_s_barrier()
#define WAIT_LGKM0() asm volatile("s_waitcnt lgkmcnt(0)" ::: "memory")
#define WAIT_VM(N)   asm volatile("s_waitcnt vmcnt(" #N ")" ::: "memory")

// Stage one 8KB chunk (128 rows x 32 cols bf16) of a K-tile into LDS.
// Dest is wave-uniform base (HW scatters lane*16B); swizzle applied by
// inverse-permuting the per-lane GLOBAL source (rule #21, XOR involution).
#define STAGE(basePtr, ko, dstUshort, chunk) \
    __builtin_amdgcn_global_load_lds( \
        (const __attribute__((address_space(1))) void*)((basePtr) + ((chunk) ? off1 : off0) + (ko)), \
        (__attribute__((address_space(3))) void*)(reinterpret_cast<char*>(dstUshort) + ((chunk) << 13) + (wave << 10)), \
        16, 0, 0)

// 16 MFMA of one phase: 4 Mfrags x 4 Nfrags, K=32.
#define PH_MFMA(mbase, AF) \
    _Pragma("unroll") for (int mf = 0; mf < 4; ++mf) \
    _Pragma("unroll") for (int nf = 0; nf < 4; ++nf) \
        acc[(mbase) + mf][nf] = __builtin_amdgcn_mfma_f32_16x16x32_bf16( \
            AF[mf], bfrag[nf], acc[(mbase) + mf][nf], 0, 0, 0)

// One K-tile = 2 phases. DOSTAGE: stage tile jj+3 into the slot of the tile
// consumed at jj-1. VMN: counted vmcnt at end of phase 2.
// Steady state (DOSTAGE=1): outstanding = tiles j+1,j+2,j+3 = 12 loads;
// WAIT_VM(8) retires tile j+1 (read next tile). Tail ladder (no stage):
// nk-3: out=8 -> VM(4) retires nk-2; nk-2: out=4 -> VM(0); nk-1: VM(0) no-op.
#define KTILE_G(slot, jj, DOSTAGE, VMN) do { \
    const unsigned short* tA = smem + (slot) * 8192; \
    const unsigned short* tB = smem + 32768 + (slot) * 8192; \
    unsigned short* dA = smem + (((slot) + 3) & 3) * 8192; \
    unsigned short* dB = smem + 32768 + (((slot) + 3) & 3) * 8192; \
    /* ---- phase 1: read B(all) + A mf0-3 (8 ds_read_b128); stage B(j+3) ---- */ \
    _Pragma("unroll") for (int nf = 0; nf < 4; ++nf) \
        bfrag[nf] = lds_frag(tB, wc * 64 + nf * 16 + ln15, kb16); \
    _Pragma("unroll") for (int mf = 0; mf < 4; ++mf) \
        afrag[mf] = lds_frag(tA, wr * 128 + mf * 16 + ln15, kb16); \
    if (DOSTAGE) { \
        const int ko3 = ((jj) + 3) << 5; \
        STAGE(baseB, ko3, dB, 0); \
        STAGE(baseB, ko3, dB, 1); \
    } \
    BARRIER(); WAIT_LGKM0(); \
    __builtin_amdgcn_s_setprio(1); PH_MFMA(0, afrag); __builtin_amdgcn_s_setprio(0); \
    BARRIER(); \
    /* ---- phase 2: read A mf4-7; stage A(j+3); counted vmcnt ---- */ \
    _Pragma("unroll") for (int mf = 0; mf < 4; ++mf) \
        afrag2[mf] = lds_frag(tA, wr * 128 + (4 + mf) * 16 + ln15, kb16); \
    if (DOSTAGE) { \
        const int ko3 = ((jj) + 3) << 5; \
        STAGE(baseA, ko3, dA, 0); \
        STAGE(baseA, ko3, dA, 1); \
    } \
    WAIT_VM(VMN); \
    BARRIER(); WAIT_LGKM0(); \
    __builtin_amdgcn_s_setprio(1); PH_MFMA(4, afrag2); __builtin_amdgcn_s_setprio(0); \
    BARRIER(); \
} while (0)

// NT GEMM, 256^2 quad-buffered 2-phase/K32: C = A[M,K] * Bm[N,K]^T.
// EPI=0: Hout = bf16(silu(C)); EPI=1: fused bias + dynamic causal conv + silu
// with LDS-staged x-window.
template <int EPI>
__global__ __launch_bounds__(512, 2)
void gemm8p(const unsigned short* __restrict__ A,
            const unsigned short* __restrict__ Bm,
            int M, int N, int K,
            unsigned short* __restrict__ Hout,
            const float* __restrict__ bias,
            const float* __restrict__ Xf,
            float* __restrict__ Out) {
    __shared__ __align__(16) unsigned short smem[65536];  // 128 KB

    const int tid  = threadIdx.x;
    const int wave = tid >> 6, lane = tid & 63;
    const int wr = wave >> 2, wc = wave & 3;        // 2M x 4N wave grid
    const int ln15 = lane & 15;
    const int kb16 = (lane >> 4) * 16;              // 16B k-slot in 64B row

    // Region-supertile XCD swizzle (bijective; needs GX%4==0, GY%2==0):
    // xcd = bid&7 owns a (GY/2 rows) x (GX/4 cols) block region, traversed
    // row-major. Consecutive 32 blocks/XCD = 4x(GX/4) patch; the region's
    // B-panels are reused across all row-steps (vs streaming all B per row).
    const int GX = gridDim.x, GY = gridDim.y;
    const int bid = blockIdx.y * GX + blockIdx.x;
    const int xcd = bid & 7;
    const int idx = bid >> 3;
    const int W_ = GX >> 2;
    const int rr = idx / W_, cc = idx % W_;
    const int by = (xcd >> 2) * (GY >> 1) + rr;
    const int bx = (xcd & 3) * W_ + cc;
    const int m0 = by * BM, n0 = bx * BN;

    const int nk = K >> 5;   // K-tiles of 32 (=64 here)

    // Per-thread staging offsets: chunk c covers rows c*128 + wave*16 + lane/4;
    // within-row 16B slot = lane&3, inverse-swizzled.
    const int r0 = (wave << 4) + (lane >> 2);
    const int r1 = 128 + r0;
    const int cb0 = ((lane & 3) << 4) ^ (((r0 >> 1) & 3) << 4);
    const int cb1 = ((lane & 3) << 4) ^ (((r1 >> 1) & 3) << 4);
    const size_t off0 = (size_t)r0 * K + (cb0 >> 1);
    const size_t off1 = (size_t)r1 * K + (cb1 >> 1);
    const unsigned short* baseA = A + (size_t)m0 * K;
    const unsigned short* baseB = Bm + (size_t)n0 * K;

    f32x4 acc[8][4];
#pragma unroll
    for (int i = 0; i < 8; ++i)
#pragma unroll
        for (int j = 0; j < 4; ++j) acc[i][j] = (f32x4)0.0f;

    bf16x8 bfrag[4], afrag[4], afrag2[4];

    // ---- prologue: stage tiles 0,1,2 ----
#pragma unroll
    for (int t = 0; t < 3; ++t) {
        const int ko = t << 5;
        unsigned short* dA = smem + t * 8192;
        unsigned short* dB = smem + 32768 + t * 8192;
        STAGE(baseB, ko, dB, 0);
        STAGE(baseB, ko, dB, 1);
        STAGE(baseA, ko, dA, 0);
        STAGE(baseA, ko, dA, 1);
    }
    WAIT_VM(8);   // tile 0 landed; tiles 1,2 in flight
    BARRIER();

    // ---- main loop: tiles 0 .. nk-5 staged-steady; tail peeled ----
    for (int it = 0; it < (nk >> 2) - 1; ++it) {
        const int j = it << 2;
        KTILE_G(0, j,     1, 8);
        KTILE_G(1, j + 1, 1, 8);
        KTILE_G(2, j + 2, 1, 8);
        KTILE_G(3, j + 3, 1, 8);
    }
    // tail: nk-4 stages nk-1; then no more stages, exact vmcnt ladder
    KTILE_G(0, nk - 4, 1, 8);
    KTILE_G(1, nk - 3, 0, 4);
    KTILE_G(2, nk - 2, 0, 0);
    KTILE_G(3, nk - 1, 0, 0);
    BARRIER();

    // ---- epilogue ----
    if (EPI == 0) {
#pragma unroll
        for (int mf = 0; mf < 8; ++mf) {
            int rowb = m0 + wr * 128 + mf * 16 + (lane >> 4) * 4;
#pragma unroll
            for (int nf = 0; nf < 4; ++nf) {
                int col = n0 + wc * 64 + nf * 16 + ln15;
#pragma unroll
                for (int r = 0; r < 4; ++r) {
                    Hout[(size_t)(rowb + r) * N + col] = f2bf(silu_f(acc[mf][nf][r]));
                }
            }
        }
    } else {
        // Stage x-window into LDS: rows ts = t0-3 .. t0+255 (259), 64 d cols.
        const int t0 = m0 & (T_DIM - 1);
        const int bidx = m0 >> 12;
        const int dbase = n0 >> 2;
        float* Xw = reinterpret_cast<float*>(smem);   // [259][XW_STRIDE]
        for (int idx2 = tid; idx2 < 259 * 16; idx2 += 512) {
            int rw = idx2 >> 4, q = (idx2 & 15) << 2;
            int ts = t0 - 3 + rw;
            float4 v = make_float4(0.f, 0.f, 0.f, 0.f);
            if (ts >= 0)
                v = *reinterpret_cast<const float4*>(
                    &Xf[((size_t)bidx * T_DIM + ts) * D_DIM + dbase + q]);
            float* p = &Xw[rw * XW_STRIDE + q];
            p[0] = v.x; p[1] = v.y; p[2] = v.z; p[3] = v.w;
        }
        __syncthreads();

        // k = C + bias; out[b,t,d] = silu(sum_w x[b,t-3+w,d] * k[t, d*4+w])
        // col -> (d = col>>2, w = col&3); 4-lane butterfly sums over w.
        const int dl = wc * 16 + (ln15 >> 2);   // + nf*4 below
        const int w = lane & 3;
#pragma unroll
        for (int mf = 0; mf < 8; ++mf) {
            int lrow0 = wr * 128 + mf * 16 + (lane >> 4) * 4;
#pragma unroll
            for (int nf = 0; nf < 4; ++nf) {
                int col = n0 + wc * 64 + nf * 16 + ln15;
                int d = col >> 2;
                float bv = bias[col];
#pragma unroll
                for (int r = 0; r < 4; ++r) {
                    int lrow = lrow0 + r;
                    float v = acc[mf][nf][r] + bv;
                    float xv = Xw[(lrow + w) * XW_STRIDE + dl + nf * 4];
                    float p = v * xv;
                    p += __shfl_xor(p, 1);
                    p += __shfl_xor(p, 2);
                    if ((lane & 3) == 0) {
                        Out[((size_t)bidx * T_DIM + (t0 + lrow)) * D_DIM + d] = silu_f(p);
                    }
                }
            }
        }
    }
}

extern "C" void kernel_launch(void* const* d_in, const int* in_sizes, int n_in,
                              void* d_out, int out_size, void* d_ws, size_t ws_size,
                              hipStream_t stream) {
    const float* x    = (const float*)d_in[0];  // [B,T,D]
    const float* w1   = (const float*)d_in[1];  // [H,D]
    const float* w2w  = (const float*)d_in[2];  // [D*W,H]
    const float* w2b  = (const float*)d_in[3];  // [D*W]
    float* out = (float*)d_out;

    // Workspace: ws0 = xb [M,D] bf16 (later reused for w2wb [N2,H] bf16),
    //            ws1 = w1b [H,D] bf16, ws2 = hb [M,H] bf16.
    unsigned short* ws0 = (unsigned short*)d_ws;
    unsigned short* ws1 = ws0 + (size_t)M_DIM * D_DIM;
    unsigned short* ws2 = ws1 + (size_t)H_DIM * D_DIM;

    const int CT = 256;
    {
        int n4 = (M_DIM * D_DIM) / 4;
        cvt_f32_to_bf16<<<(n4 + CT - 1) / CT, CT, 0, stream>>>(x, ws0, n4);
    }
    {
        int n4 = (H_DIM * D_DIM) / 4;
        cvt_f32_to_bf16<<<(n4 + CT - 1) / CT, CT, 0, stream>>>(w1, ws1, n4);
    }
    // GEMM1: hb = silu(xb @ w1b^T)  [8192, 2048]
    gemm8p<0><<<dim3(H_DIM / BN, M_DIM / BM), 512, 0, stream>>>(
        ws0, ws1, M_DIM, H_DIM, D_DIM, ws2, nullptr, nullptr, nullptr);
    // convert w2_w into ws0 (xb now dead)
    {
        int n4 = (N2_DIM * H_DIM) / 4;
        cvt_f32_to_bf16<<<(n4 + CT - 1) / CT, CT, 0, stream>>>(w2w, ws0, n4);
    }
    // GEMM2 + fused bias/conv/silu -> out
    gemm8p<1><<<dim3(N2_DIM / BN, M_DIM / BM), 512, 0, stream>>>(
        ws2, ws0, M_DIM, N2_DIM, H_DIM, nullptr, w2b, x, out);
}

// Round 6
// 402.281 us; speedup vs baseline: 1.3012x; 1.0252x over previous
//
#include <hip/hip_runtime.h>
#include <hip/hip_bf16.h>
#include <math.h>

// Problem constants (B=2, T=4096, D=2048, H=2048, W=4)
#define B_DIM 2
#define T_DIM 4096
#define D_DIM 2048
#define H_DIM 2048
#define W_K   4
#define M_DIM (B_DIM * T_DIM)   // 8192 tokens
#define N2_DIM (D_DIM * W_K)    // 8192

typedef __bf16 bf16x8 __attribute__((ext_vector_type(8)));
typedef float  f32x4  __attribute__((ext_vector_type(4)));

// m201-faithful: 256x256 tile, K-tile 64, double-buffered, 8 waves (2M x 4N),
// 4 phases/K-tile, half-tile stage schedule, vmcnt(6) once per K-tile.
#define BM 256
#define BN 256
#define BKT 64
#define XW_STRIDE 68   // f32 stride for epilogue x-window (2-way-free banks)

__device__ __forceinline__ unsigned short f2bf(float f) {
    unsigned int u = __float_as_uint(f);
    unsigned int r = (u + 0x7FFFu + ((u >> 16) & 1u)) >> 16;  // RNE
    return (unsigned short)r;
}

__device__ __forceinline__ float silu_f(float v) {
    return v / (1.0f + __expf(-v));
}

__global__ void cvt_f32_to_bf16(const float* __restrict__ in,
                                unsigned short* __restrict__ out, int n4) {
    int i = blockIdx.x * blockDim.x + threadIdx.x;
    if (i >= n4) return;
    float4 v = reinterpret_cast<const float4*>(in)[i];
    ushort4 o;
    o.x = f2bf(v.x); o.y = f2bf(v.y); o.z = f2bf(v.z); o.w = f2bf(v.w);
    reinterpret_cast<ushort4*>(out)[i] = o;
}

// LDS tile: [256 rows][64 bf16] = 128 B/row, XOR swizzle:
//   phys = r*128 + (kb ^ ((r&7)<<4))
// ds_read_b128: 16 lanes share kb with rows r..r+15 -> (r&7) spreads them over
// all 8 16B slots (32 banks); rows repeat once = exact 2-way aliasing (free).
__device__ __forceinline__ bf16x8 lds_frag(const unsigned short* buf, int r, int kb) {
    int lin = r * 128 + (kb ^ ((r & 7) << 4));
    return *reinterpret_cast<const bf16x8*>(reinterpret_cast<const char*>(buf) + lin);
}

#define BARRIER()    __builtin_amdgcn_s_barrier()
#define WAIT_LGKM0() asm volatile("s_waitcnt lgkmcnt(0)" ::: "memory")
#define WAIT_VM(N)   asm volatile("s_waitcnt vmcnt(" #N ")" ::: "memory")

// Stage one 8KB chunk (64 rows x 64 cols bf16) of a K-tile into LDS.
// global_load_lds dest = wave-uniform base + lane*16; swizzle applied by
// inverse-permuting the per-lane GLOBAL source (rule #21, XOR involution).
// Lane l covers row chunk*64 + wave*8 + (l>>3), slot ((l&7)^((l>>3)&7)).
#define STAGE64(basePtr, ko, dstUshort, chunk) \
    __builtin_amdgcn_global_load_lds( \
        (const __attribute__((address_space(1))) void*)((basePtr) + soff + (size_t)(chunk) * 64 * K + (ko)), \
        (__attribute__((address_space(3))) void*)(reinterpret_cast<char*>(dstUshort) + ((chunk) << 13) + (wave << 10)), \
        16, 0, 0)

// 16 MFMA of one phase: M-group mg (2 Mfrags) x 4 Nfrags x 2 K-steps.
#define PH_MFMA(mg) \
    _Pragma("unroll") for (int kk = 0; kk < 2; ++kk) \
    _Pragma("unroll") for (int mrel = 0; mrel < 2; ++mrel) \
    _Pragma("unroll") for (int nf = 0; nf < 4; ++nf) \
        acc[(mg)*2 + mrel][nf] = __builtin_amdgcn_mfma_f32_16x16x32_bf16( \
            afrag[mrel][kk], bfrag[nf][kk], acc[(mg)*2 + mrel][nf], 0, 0, 0)

// One K-tile = 4 phases (m201 schedule). Stage units (clobber-safe):
//   ph1: A2(j+1) -> other buf chunks 1,3 (A mg2,3 of j-1 consumed at j-1 ph3/4)
//   ph2: B1(j+2) -> this buf chunks 0,1  (B fully read at ph1)
//   ph3: A1(j+2) -> this buf chunks 0,2  (A mg0,1 read at ph1,ph2)
//   ph4: B2(j+2) -> this buf chunks 2,3; vmcnt(6) = 3 half-tiles stay in flight
// Steady state at ph4 pre-wait: 14 loads out; vmcnt(6) retires exactly
// B1,A1,B2(j+1) + A2(j+1) -> tile j+1 ready; B1,A1,B2(j+2) remain.
#define KTILE_M(bi, jj, S1, S2, S3, S4, VMN) do { \
    const unsigned short* tA = smem + (bi) * 16384; \
    const unsigned short* tB = smem + 32768 + (bi) * 16384; \
    unsigned short* oA = smem + ((bi) ^ 1) * 16384; \
    unsigned short* cA = smem + (bi) * 16384; \
    unsigned short* cB = smem + 32768 + (bi) * 16384; \
    /* ph1: read all B (8) + A mg0 (4) = 12 ds_read_b128; stage A2(j+1) */ \
    _Pragma("unroll") for (int nf = 0; nf < 4; ++nf) \
    _Pragma("unroll") for (int kk = 0; kk < 2; ++kk) \
        bfrag[nf][kk] = lds_frag(tB, wc*64 + nf*16 + ln15, kk*64 + kb16); \
    _Pragma("unroll") for (int mrel = 0; mrel < 2; ++mrel) \
    _Pragma("unroll") for (int kk = 0; kk < 2; ++kk) \
        afrag[mrel][kk] = lds_frag(tA, wr*128 + mrel*16 + ln15, kk*64 + kb16); \
    if (S1) { const int ko = ((jj) + 1) << 6; \
        STAGE64(baseA, ko, oA, 1); STAGE64(baseA, ko, oA, 3); } \
    BARRIER(); WAIT_LGKM0(); \
    __builtin_amdgcn_s_setprio(1); PH_MFMA(0); __builtin_amdgcn_s_setprio(0); \
    BARRIER(); \
    /* ph2: A mg1; stage B1(j+2) */ \
    _Pragma("unroll") for (int mrel = 0; mrel < 2; ++mrel) \
    _Pragma("unroll") for (int kk = 0; kk < 2; ++kk) \
        afrag[mrel][kk] = lds_frag(tA, wr*128 + 32 + mrel*16 + ln15, kk*64 + kb16); \
    if (S2) { const int ko = ((jj) + 2) << 6; \
        STAGE64(baseB, ko, cB, 0); STAGE64(baseB, ko, cB, 1); } \
    BARRIER(); WAIT_LGKM0(); \
    __builtin_amdgcn_s_setprio(1); PH_MFMA(1); __builtin_amdgcn_s_setprio(0); \
    BARRIER(); \
    /* ph3: A mg2; stage A1(j+2) */ \
    _Pragma("unroll") for (int mrel = 0; mrel < 2; ++mrel) \
    _Pragma("unroll") for (int kk = 0; kk < 2; ++kk) \
        afrag[mrel][kk] = lds_frag(tA, wr*128 + 64 + mrel*16 + ln15, kk*64 + kb16); \
    if (S3) { const int ko = ((jj) + 2) << 6; \
        STAGE64(baseA, ko, cA, 0); STAGE64(baseA, ko, cA, 2); } \
    BARRIER(); WAIT_LGKM0(); \
    __builtin_amdgcn_s_setprio(1); PH_MFMA(2); __builtin_amdgcn_s_setprio(0); \
    BARRIER(); \
    /* ph4: A mg3; stage B2(j+2); counted vmcnt (never drains in main loop) */ \
    _Pragma("unroll") for (int mrel = 0; mrel < 2; ++mrel) \
    _Pragma("unroll") for (int kk = 0; kk < 2; ++kk) \
        afrag[mrel][kk] = lds_frag(tA, wr*128 + 96 + mrel*16 + ln15, kk*64 + kb16); \
    if (S4) { const int ko = ((jj) + 2) << 6; \
        STAGE64(baseB, ko, cB, 2); STAGE64(baseB, ko, cB, 3); } \
    WAIT_VM(VMN); \
    BARRIER(); WAIT_LGKM0(); \
    __builtin_amdgcn_s_setprio(1); PH_MFMA(3); __builtin_amdgcn_s_setprio(0); \
    BARRIER(); \
} while (0)

// NT GEMM, 256^2 dbuf 4-phase/K64: C = A[M,K] * Bm[N,K]^T, bf16 in, fp32 acc.
// EPI=0: Hout = bf16(silu(C)); EPI=1: fused bias + dynamic causal conv + silu
// with LDS-staged x-window.
template <int EPI>
__global__ __launch_bounds__(512, 2)
void gemm8p(const unsigned short* __restrict__ A,
            const unsigned short* __restrict__ Bm,
            int M, int N, int K,
            unsigned short* __restrict__ Hout,
            const float* __restrict__ bias,
            const float* __restrict__ Xf,
            float* __restrict__ Out) {
    __shared__ __align__(16) unsigned short smem[65536];  // 128 KB

    const int tid  = threadIdx.x;
    const int wave = tid >> 6, lane = tid & 63;
    const int wr = wave >> 2, wc = wave & 3;        // 2M x 4N wave grid
    const int ln15 = lane & 15;
    const int kb16 = (lane >> 4) * 16;              // 16B k-slot within 128B row

    // Region-supertile XCD swizzle (bijective; needs GX%4==0, GY%2==0)
    const int GX = gridDim.x, GY = gridDim.y;
    const int bid = blockIdx.y * GX + blockIdx.x;
    const int xcd = bid & 7;
    const int idx = bid >> 3;
    const int W_ = GX >> 2;
    const int rr = idx / W_, cc = idx % W_;
    const int by = (xcd >> 2) * (GY >> 1) + rr;
    const int bx = (xcd & 3) * W_ + cc;
    const int m0 = by * BM, n0 = bx * BN;

    const int nk = K >> 6;   // K-tiles of 64 (=32 here)

    // Per-thread staging offset: lane l -> row wave*8 + (l>>3),
    // slot ((l&7)^((l>>3)&7)) (inverse swizzle; row&7 == (l>>3)&7).
    const int srow = (wave << 3) + (lane >> 3);
    const int scol = (((lane & 7) ^ ((lane >> 3) & 7)) << 3);  // ushort units
    const size_t soff = (size_t)srow * K + scol;
    const unsigned short* baseA = A + (size_t)m0 * K;
    const unsigned short* baseB = Bm + (size_t)n0 * K;

    f32x4 acc[8][4];
#pragma unroll
    for (int i = 0; i < 8; ++i)
#pragma unroll
        for (int j = 0; j < 4; ++j) acc[i][j] = (f32x4)0.0f;

    bf16x8 bfrag[4][2], afrag[2][2];

    // ---- prologue: tile 0 all 4 halves + tile 1's B1,A1,B2 (A2(1) at ph1) ----
    {
        unsigned short* dA0 = smem;
        unsigned short* dB0 = smem + 32768;
        unsigned short* dA1 = smem + 16384;
        unsigned short* dB1 = smem + 49152;
        STAGE64(baseB, 0, dB0, 0); STAGE64(baseB, 0, dB0, 1);
        STAGE64(baseB, 0, dB0, 2); STAGE64(baseB, 0, dB0, 3);
        STAGE64(baseA, 0, dA0, 0); STAGE64(baseA, 0, dA0, 1);
        STAGE64(baseA, 0, dA0, 2); STAGE64(baseA, 0, dA0, 3);
        STAGE64(baseB, BKT, dB1, 0); STAGE64(baseB, BKT, dB1, 1);  // B1(1)
        STAGE64(baseA, BKT, dA1, 0); STAGE64(baseA, BKT, dA1, 2);  // A1(1)
        STAGE64(baseB, BKT, dB1, 2); STAGE64(baseB, BKT, dB1, 3);  // B2(1)
    }
    WAIT_VM(6);   // tile 0 landed; tile 1's 3 halves in flight
    BARRIER();

    // ---- main loop: 2 K-tiles per iteration; last two tiles peeled ----
    for (int it = 0; it < (nk >> 1) - 1; ++it) {
        const int j = it << 1;
        KTILE_M(0, j,     1, 1, 1, 1, 6);
        KTILE_M(1, j + 1, 1, 1, 1, 1, 6);
    }
    KTILE_M(0, nk - 2, 1, 0, 0, 0, 0);   // stage only A2(nk-1); drain
    KTILE_M(1, nk - 1, 0, 0, 0, 0, 0);
    BARRIER();

    // ---- epilogue ----
    if (EPI == 0) {
#pragma unroll
        for (int mf = 0; mf < 8; ++mf) {
            int rowb = m0 + wr * 128 + mf * 16 + (lane >> 4) * 4;
#pragma unroll
            for (int nf = 0; nf < 4; ++nf) {
                int col = n0 + wc * 64 + nf * 16 + ln15;
#pragma unroll
                for (int r = 0; r < 4; ++r) {
                    Hout[(size_t)(rowb + r) * N + col] = f2bf(silu_f(acc[mf][nf][r]));
                }
            }
        }
    } else {
        // Stage x-window into LDS: rows ts = t0-3 .. t0+255 (259), 64 d cols.
        const int t0 = m0 & (T_DIM - 1);
        const int bidx = m0 >> 12;
        const int dbase = n0 >> 2;
        float* Xw = reinterpret_cast<float*>(smem);   // [259][XW_STRIDE]
        for (int idx2 = tid; idx2 < 259 * 16; idx2 += 512) {
            int rw = idx2 >> 4, q = (idx2 & 15) << 2;
            int ts = t0 - 3 + rw;
            float4 v = make_float4(0.f, 0.f, 0.f, 0.f);
            if (ts >= 0)
                v = *reinterpret_cast<const float4*>(
                    &Xf[((size_t)bidx * T_DIM + ts) * D_DIM + dbase + q]);
            float* p = &Xw[rw * XW_STRIDE + q];
            p[0] = v.x; p[1] = v.y; p[2] = v.z; p[3] = v.w;
        }
        __syncthreads();

        // k = C + bias; out[b,t,d] = silu(sum_w x[b,t-3+w,d] * k[t, d*4+w])
        // col -> (d = col>>2, w = col&3); 4-lane butterfly sums over w.
        const int dl = wc * 16 + (ln15 >> 2);   // + nf*4 below
        const int w = lane & 3;
#pragma unroll
        for (int mf = 0; mf < 8; ++mf) {
            int lrow0 = wr * 128 + mf * 16 + (lane >> 4) * 4;
#pragma unroll
            for (int nf = 0; nf < 4; ++nf) {
                int col = n0 + wc * 64 + nf * 16 + ln15;
                int d = col >> 2;
                float bv = bias[col];
#pragma unroll
                for (int r = 0; r < 4; ++r) {
                    int lrow = lrow0 + r;
                    float v = acc[mf][nf][r] + bv;
                    float xv = Xw[(lrow + w) * XW_STRIDE + dl + nf * 4];
                    float p = v * xv;
                    p += __shfl_xor(p, 1);
                    p += __shfl_xor(p, 2);
                    if ((lane & 3) == 0) {
                        Out[((size_t)bidx * T_DIM + (t0 + lrow)) * D_DIM + d] = silu_f(p);
                    }
                }
            }
        }
    }
}

extern "C" void kernel_launch(void* const* d_in, const int* in_sizes, int n_in,
                              void* d_out, int out_size, void* d_ws, size_t ws_size,
                              hipStream_t stream) {
    const float* x    = (const float*)d_in[0];  // [B,T,D]
    const float* w1   = (const float*)d_in[1];  // [H,D]
    const float* w2w  = (const float*)d_in[2];  // [D*W,H]
    const float* w2b  = (const float*)d_in[3];  // [D*W]
    float* out = (float*)d_out;

    // Workspace: ws0 = xb [M,D] bf16 (later reused for w2wb [N2,H] bf16),
    //            ws1 = w1b [H,D] bf16, ws2 = hb [M,H] bf16.
    unsigned short* ws0 = (unsigned short*)d_ws;
    unsigned short* ws1 = ws0 + (size_t)M_DIM * D_DIM;
    unsigned short* ws2 = ws1 + (size_t)H_DIM * D_DIM;

    const int CT = 256;
    {
        int n4 = (M_DIM * D_DIM) / 4;
        cvt_f32_to_bf16<<<(n4 + CT - 1) / CT, CT, 0, stream>>>(x, ws0, n4);
    }
    {
        int n4 = (H_DIM * D_DIM) / 4;
        cvt_f32_to_bf16<<<(n4 + CT - 1) / CT, CT, 0, stream>>>(w1, ws1, n4);
    }
    // GEMM1: hb = silu(xb @ w1b^T)  [8192, 2048]
    gemm8p<0><<<dim3(H_DIM / BN, M_DIM / BM), 512, 0, stream>>>(
        ws0, ws1, M_DIM, H_DIM, D_DIM, ws2, nullptr, nullptr, nullptr);
    // convert w2_w into ws0 (xb now dead)
    {
        int n4 = (N2_DIM * H_DIM) / 4;
        cvt_f32_to_bf16<<<(n4 + CT - 1) / CT, CT, 0, stream>>>(w2w, ws0, n4);
    }
    // GEMM2 + fused bias/conv/silu -> out
    gemm8p<1><<<dim3(N2_DIM / BN, M_DIM / BM), 512, 0, stream>>>(
        ws2, ws0, M_DIM, N2_DIM, H_DIM, nullptr, w2b, x, out);
}